// Round 1
// baseline (96.179 us; speedup 1.0000x reference)
//
#include <hip/hip_runtime.h>

// RoiPoolingConv: fm [64,64,1024] f32 NHWC, rois [300,4] int32 (x,y,w,h),
// out [300,14,14,1024] f32. One block per (roi,py,px); 256 threads x float4
// over the 1024 channels.

#define POOL 14
#define FMW 64
#define CH 1024

__global__ __launch_bounds__(256) void roi_pool_kernel(
    const float* __restrict__ fm,
    const int* __restrict__ rois,
    float* __restrict__ out)
{
    const int b  = blockIdx.x;              // 0 .. 300*14*14-1
    const int px = b % POOL;
    const int py = (b / POOL) % POOL;
    const int roi = b / (POOL * POOL);

    // ROI (x, y, w, h)
    const int4 r = *reinterpret_cast<const int4*>(rois + roi * 4);
    const int x = r.x, y = r.y, w = r.z, h = r.w;

    // Legacy-TF bilinear source coords (align_corners=False, no half-pixel)
    const float fy = (float)y + (float)py * ((float)h / 14.0f);
    const float fx = (float)x + (float)px * ((float)w / 14.0f);
    const int y0 = (int)floorf(fy);
    const int x0 = (int)floorf(fx);
    const int y1 = min(y0 + 1, y + h - 1);
    const int x1 = min(x0 + 1, x + w - 1);
    const float wy = fy - (float)y0;
    const float wx = fx - (float)x0;

    const float4* tlp = reinterpret_cast<const float4*>(fm + (size_t)(y0 * FMW + x0) * CH);
    const float4* trp = reinterpret_cast<const float4*>(fm + (size_t)(y0 * FMW + x1) * CH);
    const float4* blp = reinterpret_cast<const float4*>(fm + (size_t)(y1 * FMW + x0) * CH);
    const float4* brp = reinterpret_cast<const float4*>(fm + (size_t)(y1 * FMW + x1) * CH);
    float4* op = reinterpret_cast<float4*>(out + (size_t)b * CH);

    const int c = threadIdx.x;  // float4 index, 0..255 covers 1024 channels

    const float4 tl = tlp[c];
    const float4 tr = trp[c];
    const float4 bl = blp[c];
    const float4 br = brp[c];

    float4 o;
    {
        float top, bot;
        top = tl.x + wx * (tr.x - tl.x);
        bot = bl.x + wx * (br.x - bl.x);
        o.x = top + wy * (bot - top);
        top = tl.y + wx * (tr.y - tl.y);
        bot = bl.y + wx * (br.y - bl.y);
        o.y = top + wy * (bot - top);
        top = tl.z + wx * (tr.z - tl.z);
        bot = bl.z + wx * (br.z - bl.z);
        o.z = top + wy * (bot - top);
        top = tl.w + wx * (tr.w - tl.w);
        bot = bl.w + wx * (br.w - bl.w);
        o.w = top + wy * (bot - top);
    }
    op[c] = o;
}

extern "C" void kernel_launch(void* const* d_in, const int* in_sizes, int n_in,
                              void* d_out, int out_size, void* d_ws, size_t ws_size,
                              hipStream_t stream) {
    const float* fm  = (const float*)d_in[0];   // [1,64,64,1024] f32
    const int* rois  = (const int*)d_in[1];     // [1,300,4] i32
    float* out       = (float*)d_out;           // [1,300,14,14,1024] f32

    const int num_rois = in_sizes[1] / 4;       // 300
    const int blocks = num_rois * POOL * POOL;  // 58800
    roi_pool_kernel<<<blocks, 256, 0, stream>>>(fm, rois, out);
}

// Round 2
// 64.336 us; speedup vs baseline: 1.4949x; 1.4949x over previous
//
#include <hip/hip_runtime.h>

// RoiPoolingConv: fm [64,64,1024] f32 NHWC, rois [300,4] int32 (x,y,w,h),
// out [300,14,14,1024] f32.
// One block per (roi, py): 256 threads x float4 over 1024 channels, loop px.
// NT stores keep the 241 MB output stream out of L2 so fm stays cached.
// XCD swizzle gives each XCD a contiguous run of ROIs for L2 read locality.

#define POOL 14
#define FMW 64
#define CH 1024
#define C4 (CH / 4)   // 256 float4 per pixel

typedef float f4 __attribute__((ext_vector_type(4)));

__global__ __launch_bounds__(256) void roi_pool_row_kernel(
    const float* __restrict__ fm,
    const int* __restrict__ rois,
    float* __restrict__ out)
{
    // Bijective XCD-aware swizzle: grid = 300*14 = 4200, 4200 % 8 == 0.
    // XCD j (blockIdx % 8 under round-robin dispatch) handles the contiguous
    // (roi,py) range [j*525, (j+1)*525) -> ~37 consecutive ROIs per XCD.
    const int NW  = 300 * POOL;      // 4200
    const int per = NW / 8;          // 525
    const int b   = blockIdx.x;
    const int sb  = (b % 8) * per + (b / 8);

    const int py  = sb % POOL;
    const int roi = sb / POOL;

    const int4 r = *reinterpret_cast<const int4*>(rois + roi * 4);
    const int x = r.x, y = r.y, w = r.z, h = r.w;

    // Legacy-TF bilinear (align_corners=False, no half-pixel centers)
    const float fy = (float)y + (float)py * ((float)h * (1.0f / 14.0f));
    const int   y0 = (int)floorf(fy);
    const int   y1 = min(y0 + 1, y + h - 1);
    const float wy = fy - (float)y0;

    const int c = threadIdx.x;  // float4 lane over channels
    const f4* row0 = reinterpret_cast<const f4*>(fm) + (size_t)y0 * FMW * C4 + c;
    const f4* row1 = reinterpret_cast<const f4*>(fm) + (size_t)y1 * FMW * C4 + c;
    f4* op = reinterpret_cast<f4*>(out) + ((size_t)roi * POOL + py) * POOL * C4 + c;

    const float wscale = (float)w * (1.0f / 14.0f);

    #pragma unroll 2
    for (int px = 0; px < POOL; ++px) {
        const float fx = (float)x + (float)px * wscale;
        const int   x0 = (int)floorf(fx);
        const int   x1 = min(x0 + 1, x + w - 1);
        const float wx = fx - (float)x0;

        const f4 tl = row0[(size_t)x0 * C4];
        const f4 tr = row0[(size_t)x1 * C4];
        const f4 bl = row1[(size_t)x0 * C4];
        const f4 br = row1[(size_t)x1 * C4];

        const f4 top = tl + wx * (tr - tl);
        const f4 bot = bl + wx * (br - bl);
        const f4 o   = top + wy * (bot - top);

        __builtin_nontemporal_store(o, op + (size_t)px * C4);
    }
}

extern "C" void kernel_launch(void* const* d_in, const int* in_sizes, int n_in,
                              void* d_out, int out_size, void* d_ws, size_t ws_size,
                              hipStream_t stream) {
    const float* fm  = (const float*)d_in[0];   // [1,64,64,1024] f32
    const int* rois  = (const int*)d_in[1];     // [1,300,4] i32
    float* out       = (float*)d_out;           // [1,300,14,14,1024] f32

    const int num_rois = in_sizes[1] / 4;       // 300
    const int blocks = num_rois * POOL;         // 4200
    roi_pool_row_kernel<<<blocks, 256, 0, stream>>>(fm, rois, out);
}

// Round 3
// 60.180 us; speedup vs baseline: 1.5982x; 1.0691x over previous
//
#include <hip/hip_runtime.h>

// RoiPoolingConv: fm [64,64,1024] f32 NHWC, rois [300,4] int32 (x,y,w,h),
// out [300,14,14,1024] f32.
//
// Two kernels:
//  1. sort_items: counting-sort the 4200 (roi,py) work items by y0 (the fm
//     row they read) into a permutation in d_ws. Single block, ~µs.
//  2. roi_pool_row_kernel: one block per work item, 256 threads x float4 over
//     1024 channels, loop px. Items are consumed in y0-sorted order with a
//     bijective XCD swizzle -> each XCD's resident window touches only a few
//     fm rows -> reads served from its 4 MiB L2 instead of thrashing to L3.
//     NT stores keep the 241 MB output stream out of L2.

#define POOL 14
#define FMW 64
#define CH 1024
#define C4 (CH / 4)   // 256 float4 per pixel

typedef float f4 __attribute__((ext_vector_type(4)));

__global__ __launch_bounds__(1024) void sort_items_kernel(
    const int* __restrict__ rois, int num_items, int* __restrict__ perm)
{
    __shared__ int base[64];
    const int tid = threadIdx.x;

    if (tid < 64) base[tid] = 0;
    __syncthreads();

    // pass 1: histogram of y0 (row index, 0..62)
    for (int i = tid; i < num_items; i += blockDim.x) {
        const int roi = i / POOL, py = i % POOL;
        const int y = rois[roi * 4 + 1], h = rois[roi * 4 + 3];
        const float fy = (float)y + (float)py * ((float)h * (1.0f / 14.0f));
        const int y0 = (int)floorf(fy);
        atomicAdd(&base[y0 & 63], 1);
    }
    __syncthreads();

    // exclusive scan (64 bins, one thread)
    if (tid == 0) {
        int s = 0;
        for (int k = 0; k < 64; ++k) { int c = base[k]; base[k] = s; s += c; }
    }
    __syncthreads();

    // pass 2: scatter item ids into sorted positions
    for (int i = tid; i < num_items; i += blockDim.x) {
        const int roi = i / POOL, py = i % POOL;
        const int y = rois[roi * 4 + 1], h = rois[roi * 4 + 3];
        const float fy = (float)y + (float)py * ((float)h * (1.0f / 14.0f));
        const int y0 = (int)floorf(fy);
        const int pos = atomicAdd(&base[y0 & 63], 1);
        perm[pos] = i;
    }
}

__global__ __launch_bounds__(256) void roi_pool_row_kernel(
    const float* __restrict__ fm,
    const int* __restrict__ rois,
    const int* __restrict__ perm,
    int nw,
    float* __restrict__ out)
{
    // Bijective XCD-aware swizzle (nw % 8 == 0): XCD j gets the contiguous
    // sorted range [j*per, (j+1)*per) -> a narrow y0 band per XCD.
    const int per = nw >> 3;
    const int b   = blockIdx.x;
    const int sb  = (b & 7) * per + (b >> 3);
    const int item = perm[sb];

    const int py  = item % POOL;
    const int roi = item / POOL;

    const int4 r = *reinterpret_cast<const int4*>(rois + roi * 4);
    const int x = r.x, y = r.y, w = r.z, h = r.w;

    // Legacy-TF bilinear (align_corners=False, no half-pixel centers)
    const float fy = (float)y + (float)py * ((float)h * (1.0f / 14.0f));
    const int   y0 = (int)floorf(fy);
    const int   y1 = min(y0 + 1, y + h - 1);
    const float wy = fy - (float)y0;

    const int c = threadIdx.x;  // float4 lane over channels
    const f4* row0 = reinterpret_cast<const f4*>(fm) + (size_t)y0 * FMW * C4 + c;
    const f4* row1 = reinterpret_cast<const f4*>(fm) + (size_t)y1 * FMW * C4 + c;
    f4* op = reinterpret_cast<f4*>(out) + ((size_t)roi * POOL + py) * POOL * C4 + c;

    const float wscale = (float)w * (1.0f / 14.0f);

    #pragma unroll 2
    for (int px = 0; px < POOL; ++px) {
        const float fx = (float)x + (float)px * wscale;
        const int   x0 = (int)floorf(fx);
        const int   x1 = min(x0 + 1, x + w - 1);
        const float wx = fx - (float)x0;

        const f4 tl = row0[(size_t)x0 * C4];
        const f4 tr = row0[(size_t)x1 * C4];
        const f4 bl = row1[(size_t)x0 * C4];
        const f4 br = row1[(size_t)x1 * C4];

        const f4 top = tl + wx * (tr - tl);
        const f4 bot = bl + wx * (br - bl);
        const f4 o   = top + wy * (bot - top);

        __builtin_nontemporal_store(o, op + (size_t)px * C4);
    }
}

// Fallback without permutation (if ws is too small): identity order.
__global__ __launch_bounds__(256) void roi_pool_row_kernel_noperm(
    const float* __restrict__ fm,
    const int* __restrict__ rois,
    int nw,
    float* __restrict__ out)
{
    const int per = nw >> 3;
    const int b   = blockIdx.x;
    const int sb  = (nw & 7) ? b : (b & 7) * per + (b >> 3);

    const int py  = sb % POOL;
    const int roi = sb / POOL;

    const int4 r = *reinterpret_cast<const int4*>(rois + roi * 4);
    const int x = r.x, y = r.y, w = r.z, h = r.w;

    const float fy = (float)y + (float)py * ((float)h * (1.0f / 14.0f));
    const int   y0 = (int)floorf(fy);
    const int   y1 = min(y0 + 1, y + h - 1);
    const float wy = fy - (float)y0;

    const int c = threadIdx.x;
    const f4* row0 = reinterpret_cast<const f4*>(fm) + (size_t)y0 * FMW * C4 + c;
    const f4* row1 = reinterpret_cast<const f4*>(fm) + (size_t)y1 * FMW * C4 + c;
    f4* op = reinterpret_cast<f4*>(out) + ((size_t)roi * POOL + py) * POOL * C4 + c;

    const float wscale = (float)w * (1.0f / 14.0f);

    #pragma unroll 2
    for (int px = 0; px < POOL; ++px) {
        const float fx = (float)x + (float)px * wscale;
        const int   x0 = (int)floorf(fx);
        const int   x1 = min(x0 + 1, x + w - 1);
        const float wx = fx - (float)x0;

        const f4 tl = row0[(size_t)x0 * C4];
        const f4 tr = row0[(size_t)x1 * C4];
        const f4 bl = row1[(size_t)x0 * C4];
        const f4 br = row1[(size_t)x1 * C4];

        const f4 top = tl + wx * (tr - tl);
        const f4 bot = bl + wx * (br - bl);
        const f4 o   = top + wy * (bot - top);

        __builtin_nontemporal_store(o, op + (size_t)px * C4);
    }
}

extern "C" void kernel_launch(void* const* d_in, const int* in_sizes, int n_in,
                              void* d_out, int out_size, void* d_ws, size_t ws_size,
                              hipStream_t stream) {
    const float* fm  = (const float*)d_in[0];   // [1,64,64,1024] f32
    const int* rois  = (const int*)d_in[1];     // [1,300,4] i32
    float* out       = (float*)d_out;           // [1,300,14,14,1024] f32

    const int num_rois = in_sizes[1] / 4;       // 300
    const int nw = num_rois * POOL;             // 4200 work items

    if (ws_size >= (size_t)nw * sizeof(int) && (nw & 7) == 0) {
        int* perm = (int*)d_ws;
        sort_items_kernel<<<1, 1024, 0, stream>>>(rois, nw, perm);
        roi_pool_row_kernel<<<nw, 256, 0, stream>>>(fm, rois, perm, nw, out);
    } else {
        roi_pool_row_kernel_noperm<<<nw, 256, 0, stream>>>(fm, rois, nw, out);
    }
}